// Round 1
// 665.809 us; speedup vs baseline: 1.1052x; 1.1052x over previous
//
#include <hip/hip_runtime.h>

#define DEV __device__ __forceinline__

typedef short bf16x8 __attribute__((ext_vector_type(8)));
typedef float f32x4 __attribute__((ext_vector_type(4)));
typedef unsigned int u32;
typedef __attribute__((address_space(1))) const u32* gas_ptr;
typedef __attribute__((address_space(3))) u32* las_ptr;

// ---------- helpers ----------
DEV short f2bf(float f) {
  union { float f; unsigned u; } un; un.f = f;
  unsigned r = un.u + 0x7FFFu + ((un.u >> 16) & 1u);  // RNE
  return (short)(r >> 16);
}
DEV float bf2f(unsigned short s) {
  union { unsigned u; float f; } un;
  un.u = ((unsigned)s) << 16;
  return un.f;
}
DEV void gload16(const short* g, short* l) {
  // async global->LDS, 16B per lane; LDS dest = wave-uniform base + lane*16
  __builtin_amdgcn_global_load_lds((gas_ptr)g, (las_ptr)l, 16, 0, 0);
}
DEV float hsum4(float4 v) { return v.x + v.y + v.z + v.w; }

// ---------- weight pack: transpose + bf16 cast ----------
// wT_offaw now padded to 512 rows (288 off + 144 aw + 80 zero)
__global__ __launch_bounds__(256) void pack_weights_kernel(
    const float* __restrict__ w_val, const float* __restrict__ w_off,
    const float* __restrict__ w_aw, const float* __restrict__ w_out,
    const float* __restrict__ b_off, const float* __restrict__ b_aw,
    short* __restrict__ wT_val, short* __restrict__ wT_offaw,
    short* __restrict__ wT_out, float* __restrict__ bias_cat) {
  int gid = blockIdx.x * 256 + threadIdx.x;
  const int S0 = 768 * 384, S1 = 768 * 288, S2 = 768 * 144, S3 = 384 * 768;
  const int S4 = 80 * 768, S5 = 512;
  if (gid < S0) { int k = gid / 384, n = gid % 384; wT_val[n * 768 + k] = f2bf(w_val[gid]); return; }
  gid -= S0;
  if (gid < S1) { int k = gid / 288, n = gid % 288; wT_offaw[n * 768 + k] = f2bf(w_off[gid]); return; }
  gid -= S1;
  if (gid < S2) { int k = gid / 144, n = gid % 144; wT_offaw[(288 + n) * 768 + k] = f2bf(w_aw[gid]); return; }
  gid -= S2;
  if (gid < S3) { int k = gid / 768, n = gid % 768; wT_out[n * 384 + k] = f2bf(w_out[gid]); return; }
  gid -= S3;
  if (gid < S4) { wT_offaw[432 * 768 + gid] = 0; return; }
  gid -= S4;
  if (gid < S5) { bias_cat[gid] = (gid < 288) ? b_off[gid] : (gid < 432 ? b_aw[gid - 288] : 0.f); }
}

// ---------- fused LayerNorm -> bf16, wave-per-row, barrier-free ----------
// 4 rows/block (1 per wave). float4 loads (16B/lane), __shfl_xor butterfly
// reductions, no LDS/syncthreads on the critical path.
__global__ __launch_bounds__(256) void ln_norm4_kernel(
    const float* __restrict__ x, const float* __restrict__ w,
    const float* __restrict__ b, short* __restrict__ y) {
  const int wv = threadIdx.x >> 6, lane = threadIdx.x & 63;
  const int row = blockIdx.x * 4 + wv;
  const float* xr = x + (size_t)row * 768;
  float4 v0 = *(const float4*)(xr + lane * 4);
  float4 v1 = *(const float4*)(xr + 256 + lane * 4);
  float4 v2 = *(const float4*)(xr + 512 + lane * 4);
  float s = hsum4(v0) + hsum4(v1) + hsum4(v2);
  #pragma unroll
  for (int off = 32; off > 0; off >>= 1) s += __shfl_xor(s, off, 64);
  const float mu = s * (1.f / 768.f);
  float4 d0 = make_float4(v0.x - mu, v0.y - mu, v0.z - mu, v0.w - mu);
  float4 d1 = make_float4(v1.x - mu, v1.y - mu, v1.z - mu, v1.w - mu);
  float4 d2 = make_float4(v2.x - mu, v2.y - mu, v2.z - mu, v2.w - mu);
  float vs = d0.x * d0.x + d0.y * d0.y + d0.z * d0.z + d0.w * d0.w +
             d1.x * d1.x + d1.y * d1.y + d1.z * d1.z + d1.w * d1.w +
             d2.x * d2.x + d2.y * d2.y + d2.z * d2.z + d2.w * d2.w;
  #pragma unroll
  for (int off = 32; off > 0; off >>= 1) vs += __shfl_xor(vs, off, 64);
  const float rs = rsqrtf(vs * (1.f / 768.f) + 1e-6f);
  const float4 w0 = *(const float4*)(w + lane * 4);
  const float4 w1 = *(const float4*)(w + 256 + lane * 4);
  const float4 w2 = *(const float4*)(w + 512 + lane * 4);
  const float4 b0 = *(const float4*)(b + lane * 4);
  const float4 b1 = *(const float4*)(b + 256 + lane * 4);
  const float4 b2 = *(const float4*)(b + 512 + lane * 4);
  unsigned short* yr = (unsigned short*)y + (size_t)row * 768;
  ushort4 o;
  o.x = (unsigned short)f2bf(d0.x * rs * w0.x + b0.x);
  o.y = (unsigned short)f2bf(d0.y * rs * w0.y + b0.y);
  o.z = (unsigned short)f2bf(d0.z * rs * w0.z + b0.z);
  o.w = (unsigned short)f2bf(d0.w * rs * w0.w + b0.w);
  *(ushort4*)(yr + lane * 4) = o;
  o.x = (unsigned short)f2bf(d1.x * rs * w1.x + b1.x);
  o.y = (unsigned short)f2bf(d1.y * rs * w1.y + b1.y);
  o.z = (unsigned short)f2bf(d1.z * rs * w1.z + b1.z);
  o.w = (unsigned short)f2bf(d1.w * rs * w1.w + b1.w);
  *(ushort4*)(yr + 256 + lane * 4) = o;
  o.x = (unsigned short)f2bf(d2.x * rs * w2.x + b2.x);
  o.y = (unsigned short)f2bf(d2.y * rs * w2.y + b2.y);
  o.z = (unsigned short)f2bf(d2.z * rs * w2.z + b2.z);
  o.w = (unsigned short)f2bf(d2.w * rs * w2.w + b2.w);
  *(ushort4*)(yr + 512 + lane * 4) = o;
}

// ---------- 128x128 bf16 MFMA GEMM, async global->LDS staging ----------
// XOR-swizzled LDS: tile [128 rows][32 k] stored as 64 lines x 8 granules(16B);
// A[r][q*8..] lives at (line=r>>1, pos=((r&1)*4+q)^(line&7)). Staging writes
// linear granules (global_load_lds constraint); ds_read_b128 fragments hit 8
// distinct bank-quads x2 => conflict-free. 4 waves 2x2, each 4x4 16x16x32 MFMA.
// Bijective XCD-chunked blockIdx swizzle (grid size must be divisible by 8):
// the consecutive logical tiles sharing an A-panel stay on one XCD's L2.
// EMODE 0: bf16 out (acc+bias); EMODE 1: f32 out (acc+bias);
// EMODE 2: f32 qres + gamma*(acc+bias)
template <int EMODE>
__global__ __launch_bounds__(256, 3) void gemm128_kernel(
    const short* __restrict__ A, const short* __restrict__ Wt,
    const float* __restrict__ bias, const float* __restrict__ qres,
    const float* __restrict__ gamma, void* __restrict__ Cout,
    const int N, const int K) {
  __shared__ __align__(16) short As[128 * 32];
  __shared__ __align__(16) short Bs[128 * 32];
  const int tid = threadIdx.x;
  const int wave = tid >> 6, lane = tid & 63;

  // XCD swizzle: dispatch id (x fastest) -> contiguous logical chunk per XCD
  const int nx = gridDim.x;
  const int id = blockIdx.y * nx + blockIdx.x;
  const int cpx = (nx * gridDim.y) >> 3;
  const int swz = (id & 7) * cpx + (id >> 3);
  const int n0 = (swz % nx) * 128, row0 = (swz / nx) * 128;

  const int lr = lane & 15, quad = lane >> 4;
  const int wm = wave >> 1, wn = wave & 1;

  // staging source coords: round rnd granule G = rnd*256 + wave*64 + lane
  const short* gA[2]; const short* gB[2];
  #pragma unroll
  for (int rnd = 0; rnd < 2; rnd++) {
    int G = rnd * 256 + wave * 64 + lane;
    int line = G >> 3, pos = G & 7, x = pos ^ (line & 7);
    int r = line * 2 + (x >> 2), qk = (x & 3) * 8;
    gA[rnd] = A + (size_t)(row0 + r) * K + qk;
    gB[rnd] = Wt + (size_t)(n0 + r) * K + qk;
  }
  short* ldsA[2] = {&As[(wave * 64) * 8], &As[(256 + wave * 64) * 8]};
  short* ldsB[2] = {&Bs[(wave * 64) * 8], &Bs[(256 + wave * 64) * 8]};

  // fragment read addresses (fixed)
  const short* aF[4]; const short* bF[4];
  #pragma unroll
  for (int t4 = 0; t4 < 4; t4++) {
    int r = wm * 64 + t4 * 16 + lr;
    int line = r >> 1, pos = ((r & 1) * 4 + quad) ^ (line & 7);
    aF[t4] = &As[(line * 8 + pos) * 8];
    int rb = wn * 64 + t4 * 16 + lr;
    int lineb = rb >> 1, posb = ((rb & 1) * 4 + quad) ^ (lineb & 7);
    bF[t4] = &Bs[(lineb * 8 + posb) * 8];
  }

  f32x4 acc[4][4];
  #pragma unroll
  for (int i = 0; i < 4; i++)
    #pragma unroll
    for (int j = 0; j < 4; j++)
      #pragma unroll
      for (int e = 0; e < 4; e++) acc[i][j][e] = 0.f;

  for (int k0 = 0; k0 < K; k0 += 32) {
    gload16(gA[0], ldsA[0]);
    gload16(gA[1], ldsA[1]);
    gload16(gB[0], ldsB[0]);
    gload16(gB[1], ldsB[1]);
    gA[0] += 32; gA[1] += 32; gB[0] += 32; gB[1] += 32;
    __syncthreads();
    bf16x8 av[4], bv[4];
    #pragma unroll
    for (int t4 = 0; t4 < 4; t4++) {
      av[t4] = *(const bf16x8*)aF[t4];
      bv[t4] = *(const bf16x8*)bF[t4];
    }
    #pragma unroll
    for (int ct = 0; ct < 4; ct++)
      #pragma unroll
      for (int rt = 0; rt < 4; rt++)
        acc[rt][ct] = __builtin_amdgcn_mfma_f32_16x16x32_bf16(av[rt], bv[ct], acc[rt][ct], 0, 0, 0);
    __syncthreads();
  }

  // epilogue: tile col = lane&15, row = quad*4+i
  #pragma unroll
  for (int ct = 0; ct < 4; ct++) {
    const int n = n0 + wn * 64 + ct * 16 + lr;
    const float bs = bias[n];
    const float gm = (EMODE == 2) ? gamma[n] : 0.f;
    #pragma unroll
    for (int rt = 0; rt < 4; rt++) {
      #pragma unroll
      for (int i = 0; i < 4; i++) {
        const int m = row0 + wm * 64 + rt * 16 + quad * 4 + i;
        float v = acc[rt][ct][i] + bs;
        if (EMODE == 0) {
          ((short*)Cout)[(size_t)m * N + n] = f2bf(v);
        } else if (EMODE == 1) {
          ((float*)Cout)[(size_t)m * N + n] = v;
        } else {
          ((float*)Cout)[(size_t)m * N + n] = qres[(size_t)m * N + n] + gm * v;
        }
      }
    }
  }
}

// ---------- sampler: softmax + bilinear gather + weighted sum ----------
__global__ __launch_bounds__(384) void sampler_kernel(
    const float* __restrict__ offaw,  // [16384][512] (cols 448..511 unused)
    const float* __restrict__ refp,   // [B][LQ][3][2]
    const short* __restrict__ value,  // bf16 [B*5376][384]
    short* __restrict__ o) {          // bf16 [16384][384]
  const int tid = threadIdx.x;
  const int qi = tid / 96, t = tid % 96;
  const int head = t >> 3, ln4 = t & 7;
  const int bq = blockIdx.x * 4 + qi;
  __shared__ __align__(16) float s[4][440];
  __shared__ float sref[4][6];
  const float* row = offaw + (size_t)bq * 512;
  #pragma unroll
  for (int i = t; i < 108; i += 96)
    *(float4*)&s[qi][i * 4] = *(const float4*)&row[i * 4];
  if (t < 6) sref[qi][t] = refp[(size_t)bq * 6 + t];
  __syncthreads();

  const float* awp = &s[qi][288 + head * 12];
  float mx = awp[0];
  #pragma unroll
  for (int j = 1; j < 12; j++) mx = fmaxf(mx, awp[j]);
  float wgt[12];
  float ssum = 0.f;
  #pragma unroll
  for (int j = 0; j < 12; j++) { float e = __expf(awp[j] - mx); wgt[j] = e; ssum += e; }
  const float inv = 1.f / ssum;

  const int b = bq >> 10;
  const unsigned short* vb =
      (const unsigned short*)value + (size_t)b * 5376 * 384 + head * 32 + ln4 * 4;
  float4 acc = make_float4(0.f, 0.f, 0.f, 0.f);
  const int HW[3] = {64, 32, 16};
  const int starts[3] = {0, 4096, 5120};
  #pragma unroll
  for (int l = 0; l < 3; l++) {
    const int Wi = HW[l];
    const float Wf = (float)Wi;
    const float rx = sref[qi][l * 2], ry = sref[qi][l * 2 + 1];
    const unsigned short* base = vb + (size_t)starts[l] * 384;
    #pragma unroll
    for (int p = 0; p < 4; p++) {
      const int oi = ((head * 3 + l) * 4 + p) * 2;
      float x = fmaf(rx, Wf, s[qi][oi] - 0.5f);
      float y = fmaf(ry, Wf, s[qi][oi + 1] - 0.5f);
      float xf = floorf(x), yf = floorf(y);
      float dx = x - xf, dy = y - yf;
      int x0 = (int)xf, y0 = (int)yf;
      int x1 = x0 + 1, y1 = y0 + 1;
      int x0c = min(max(x0, 0), Wi - 1), x1c = min(max(x1, 0), Wi - 1);
      int y0c = min(max(y0, 0), Wi - 1), y1c = min(max(y1, 0), Wi - 1);
      float wx0 = (x0 >= 0 && x0 < Wi) ? (1.f - dx) : 0.f;
      float wx1 = (x1 < Wi && x1 >= 0) ? dx : 0.f;
      float wy0 = (y0 >= 0 && y0 < Wi) ? (1.f - dy) : 0.f;
      float wy1 = (y1 < Wi && y1 >= 0) ? dy : 0.f;
      const ushort4 u00 = *(const ushort4*)(base + (size_t)(y0c * Wi + x0c) * 384);
      const ushort4 u01 = *(const ushort4*)(base + (size_t)(y0c * Wi + x1c) * 384);
      const ushort4 u10 = *(const ushort4*)(base + (size_t)(y1c * Wi + x0c) * 384);
      const ushort4 u11 = *(const ushort4*)(base + (size_t)(y1c * Wi + x1c) * 384);
      const float w00 = wx0 * wy0, w01 = wx1 * wy0, w10 = wx0 * wy1, w11 = wx1 * wy1;
      const float g = wgt[l * 4 + p];
      acc.x += g * (w00 * bf2f(u00.x) + w01 * bf2f(u01.x) + w10 * bf2f(u10.x) + w11 * bf2f(u11.x));
      acc.y += g * (w00 * bf2f(u00.y) + w01 * bf2f(u01.y) + w10 * bf2f(u10.y) + w11 * bf2f(u11.y));
      acc.z += g * (w00 * bf2f(u00.z) + w01 * bf2f(u01.z) + w10 * bf2f(u10.z) + w11 * bf2f(u11.z));
      acc.w += g * (w00 * bf2f(u00.w) + w01 * bf2f(u01.w) + w10 * bf2f(u10.w) + w11 * bf2f(u11.w));
    }
  }
  ushort4 outv;
  outv.x = (unsigned short)f2bf(acc.x * inv);
  outv.y = (unsigned short)f2bf(acc.y * inv);
  outv.z = (unsigned short)f2bf(acc.z * inv);
  outv.w = (unsigned short)f2bf(acc.w * inv);
  *(ushort4*)((unsigned short*)o + (size_t)bq * 384 + head * 32 + ln4 * 4) = outv;
}

// ---------- launch ----------
extern "C" void kernel_launch(void* const* d_in, const int* in_sizes, int n_in,
                              void* d_out, int out_size, void* d_ws, size_t ws_size,
                              hipStream_t stream) {
  (void)in_sizes; (void)n_in; (void)out_size; (void)ws_size;
  const float* q     = (const float*)d_in[0];
  const float* refp  = (const float*)d_in[1];
  const float* kv    = (const float*)d_in[2];
  const float* ln1w  = (const float*)d_in[5];
  const float* ln1b  = (const float*)d_in[6];
  const float* ln2w  = (const float*)d_in[7];
  const float* ln2b  = (const float*)d_in[8];
  const float* gamma = (const float*)d_in[9];
  const float* w_off = (const float*)d_in[10];
  const float* b_off = (const float*)d_in[11];
  const float* w_aw  = (const float*)d_in[12];
  const float* b_aw  = (const float*)d_in[13];
  const float* w_val = (const float*)d_in[14];
  const float* b_val = (const float*)d_in[15];
  const float* w_out = (const float*)d_in[16];
  const float* b_out = (const float*)d_in[17];
  float* out = (float*)d_out;

  char* wsp = (char*)d_ws;
  size_t cur = 0;
  auto alloc = [&](size_t bytes) -> void* {
    cur = (cur + 255) & ~(size_t)255;
    void* p = wsp + cur;
    cur += bytes;
    return p;
  };
  short*  wT_val   = (short*)alloc((size_t)384 * 768 * 2);
  short*  wT_offaw = (short*)alloc((size_t)512 * 768 * 2);
  short*  wT_out   = (short*)alloc((size_t)768 * 384 * 2);
  float*  bias_cat = (float*)alloc((size_t)512 * 4);
  short*  kvn      = (short*)alloc((size_t)86016 * 768 * 2);
  short*  qn       = (short*)alloc((size_t)16384 * 768 * 2);
  short*  value    = (short*)alloc((size_t)86016 * 384 * 2);
  float*  offaw    = (float*)alloc((size_t)16384 * 512 * 4);
  short*  obuf     = (short*)alloc((size_t)16384 * 384 * 2);

  pack_weights_kernel<<<3842, 256, 0, stream>>>(w_val, w_off, w_aw, w_out, b_off,
                                                b_aw, wT_val, wT_offaw, wT_out,
                                                bias_cat);
  ln_norm4_kernel<<<21504, 256, 0, stream>>>(kv, ln2w, ln2b, kvn);
  ln_norm4_kernel<<<4096, 256, 0, stream>>>(q, ln1w, ln1b, qn);
  // value = kvn @ w_val + b_val   (M=86016, N=384, K=768) -> bf16
  gemm128_kernel<0><<<dim3(3, 672), 256, 0, stream>>>(
      kvn, wT_val, b_val, nullptr, nullptr, value, 384, 768);
  // offaw = qn @ [w_off|w_aw|pad] + bias  (M=16384, N=512(pad), K=768) -> f32
  gemm128_kernel<1><<<dim3(4, 128), 256, 0, stream>>>(
      qn, wT_offaw, bias_cat, nullptr, nullptr, offaw, 512, 768);
  // sampling + attention-weighted sum -> obuf bf16 (16384 x 384)
  sampler_kernel<<<4096, 384, 0, stream>>>(offaw, refp, value, obuf);
  // out = q + gamma * (obuf @ w_out + b_out)  (M=16384, N=768, K=384)
  gemm128_kernel<2><<<dim3(6, 128), 256, 0, stream>>>(
      obuf, wT_out, b_out, q, gamma, out, 768, 384);
}

// Round 2
// 651.000 us; speedup vs baseline: 1.1304x; 1.0227x over previous
//
#include <hip/hip_runtime.h>

#define DEV __device__ __forceinline__

typedef short bf16x8 __attribute__((ext_vector_type(8)));
typedef float f32x4 __attribute__((ext_vector_type(4)));
typedef unsigned int u32;
typedef __attribute__((address_space(1))) const u32* gas_ptr;
typedef __attribute__((address_space(3))) u32* las_ptr;

// ---------- helpers ----------
DEV short f2bf(float f) {
  union { float f; unsigned u; } un; un.f = f;
  unsigned r = un.u + 0x7FFFu + ((un.u >> 16) & 1u);  // RNE
  return (short)(r >> 16);
}
DEV float bf2f(unsigned short s) {
  union { unsigned u; float f; } un;
  un.u = ((unsigned)s) << 16;
  return un.f;
}
DEV void gload16(const short* g, short* l) {
  // async global->LDS, 16B per lane; LDS dest = wave-uniform base + lane*16
  __builtin_amdgcn_global_load_lds((gas_ptr)g, (las_ptr)l, 16, 0, 0);
}
DEV float hsum4(float4 v) { return v.x + v.y + v.z + v.w; }

// ---------- weight pack: transpose + bf16 cast ----------
// wT_offaw padded to 512 rows (288 off + 144 aw + 80 zero)
__global__ __launch_bounds__(256) void pack_weights_kernel(
    const float* __restrict__ w_val, const float* __restrict__ w_off,
    const float* __restrict__ w_aw, const float* __restrict__ w_out,
    const float* __restrict__ b_off, const float* __restrict__ b_aw,
    short* __restrict__ wT_val, short* __restrict__ wT_offaw,
    short* __restrict__ wT_out, float* __restrict__ bias_cat) {
  int gid = blockIdx.x * 256 + threadIdx.x;
  const int S0 = 768 * 384, S1 = 768 * 288, S2 = 768 * 144, S3 = 384 * 768;
  const int S4 = 80 * 768, S5 = 512;
  if (gid < S0) { int k = gid / 384, n = gid % 384; wT_val[n * 768 + k] = f2bf(w_val[gid]); return; }
  gid -= S0;
  if (gid < S1) { int k = gid / 288, n = gid % 288; wT_offaw[n * 768 + k] = f2bf(w_off[gid]); return; }
  gid -= S1;
  if (gid < S2) { int k = gid / 144, n = gid % 144; wT_offaw[(288 + n) * 768 + k] = f2bf(w_aw[gid]); return; }
  gid -= S2;
  if (gid < S3) { int k = gid / 768, n = gid % 768; wT_out[n * 384 + k] = f2bf(w_out[gid]); return; }
  gid -= S3;
  if (gid < S4) { wT_offaw[432 * 768 + gid] = 0; return; }
  gid -= S4;
  if (gid < S5) { bias_cat[gid] = (gid < 288) ? b_off[gid] : (gid < 432 ? b_aw[gid - 288] : 0.f); }
}

// ---------- fused LayerNorm -> bf16, wave-per-row, barrier-free ----------
__global__ __launch_bounds__(256) void ln_norm4_kernel(
    const float* __restrict__ x, const float* __restrict__ w,
    const float* __restrict__ b, short* __restrict__ y) {
  const int wv = threadIdx.x >> 6, lane = threadIdx.x & 63;
  const int row = blockIdx.x * 4 + wv;
  const float* xr = x + (size_t)row * 768;
  float4 v0 = *(const float4*)(xr + lane * 4);
  float4 v1 = *(const float4*)(xr + 256 + lane * 4);
  float4 v2 = *(const float4*)(xr + 512 + lane * 4);
  float s = hsum4(v0) + hsum4(v1) + hsum4(v2);
  #pragma unroll
  for (int off = 32; off > 0; off >>= 1) s += __shfl_xor(s, off, 64);
  const float mu = s * (1.f / 768.f);
  float4 d0 = make_float4(v0.x - mu, v0.y - mu, v0.z - mu, v0.w - mu);
  float4 d1 = make_float4(v1.x - mu, v1.y - mu, v1.z - mu, v1.w - mu);
  float4 d2 = make_float4(v2.x - mu, v2.y - mu, v2.z - mu, v2.w - mu);
  float vs = d0.x * d0.x + d0.y * d0.y + d0.z * d0.z + d0.w * d0.w +
             d1.x * d1.x + d1.y * d1.y + d1.z * d1.z + d1.w * d1.w +
             d2.x * d2.x + d2.y * d2.y + d2.z * d2.z + d2.w * d2.w;
  #pragma unroll
  for (int off = 32; off > 0; off >>= 1) vs += __shfl_xor(vs, off, 64);
  const float rs = rsqrtf(vs * (1.f / 768.f) + 1e-6f);
  const float4 w0 = *(const float4*)(w + lane * 4);
  const float4 w1 = *(const float4*)(w + 256 + lane * 4);
  const float4 w2 = *(const float4*)(w + 512 + lane * 4);
  const float4 b0 = *(const float4*)(b + lane * 4);
  const float4 b1 = *(const float4*)(b + 256 + lane * 4);
  const float4 b2 = *(const float4*)(b + 512 + lane * 4);
  unsigned short* yr = (unsigned short*)y + (size_t)row * 768;
  ushort4 o;
  o.x = (unsigned short)f2bf(d0.x * rs * w0.x + b0.x);
  o.y = (unsigned short)f2bf(d0.y * rs * w0.y + b0.y);
  o.z = (unsigned short)f2bf(d0.z * rs * w0.z + b0.z);
  o.w = (unsigned short)f2bf(d0.w * rs * w0.w + b0.w);
  *(ushort4*)(yr + lane * 4) = o;
  o.x = (unsigned short)f2bf(d1.x * rs * w1.x + b1.x);
  o.y = (unsigned short)f2bf(d1.y * rs * w1.y + b1.y);
  o.z = (unsigned short)f2bf(d1.z * rs * w1.z + b1.z);
  o.w = (unsigned short)f2bf(d1.w * rs * w1.w + b1.w);
  *(ushort4*)(yr + 256 + lane * 4) = o;
  o.x = (unsigned short)f2bf(d2.x * rs * w2.x + b2.x);
  o.y = (unsigned short)f2bf(d2.y * rs * w2.y + b2.y);
  o.z = (unsigned short)f2bf(d2.z * rs * w2.z + b2.z);
  o.w = (unsigned short)f2bf(d2.w * rs * w2.w + b2.w);
  *(ushort4*)(yr + 512 + lane * 4) = o;
}

// ---------- 128x128 bf16 MFMA GEMM, BK=64, async global->LDS staging ----------
// LDS tile: 128 lines (1 row each) x 8 granules(16B) per matrix (16 KB).
// Granule g = row*8 + pos holds A[row][k: x*8..x*8+8) with x = pos ^ (row&7).
// Staging writes granules linearly (global_load_lds constraint) with the
// inverse-permuted global source; ds_read_b128 fragments then hit each
// bank-quad with exactly 8 lanes => conflict-free minimum.
// 32 MFMA per barrier pair (2 k-steps of 16x16x32). 4 waves 2x2, 4x4 acc.
// Bijective XCD-chunked blockIdx swizzle (grid div by 8).
// EMODE 0: bf16 out (acc+bias); 1: f32 out (acc+bias); 2: f32 qres+gamma*(acc+bias)
template <int EMODE>
__global__ __launch_bounds__(256, 3) void gemm128_kernel(
    const short* __restrict__ A, const short* __restrict__ Wt,
    const float* __restrict__ bias, const float* __restrict__ qres,
    const float* __restrict__ gamma, void* __restrict__ Cout,
    const int N, const int K) {
  __shared__ __align__(16) short As[128 * 64];
  __shared__ __align__(16) short Bs[128 * 64];
  const int tid = threadIdx.x;
  const int wave = tid >> 6, lane = tid & 63;

  // XCD swizzle: dispatch id (x fastest) -> contiguous logical chunk per XCD
  const int nx = gridDim.x;
  const int id = blockIdx.y * nx + blockIdx.x;
  const int cpx = (nx * gridDim.y) >> 3;
  const int swz = (id & 7) * cpx + (id >> 3);
  const int n0 = (swz % nx) * 128, row0 = (swz / nx) * 128;

  const int lr = lane & 15, quad = lane >> 4;
  const int wm = wave >> 1, wn = wave & 1;

  // staging: 4 rounds x 256 granules per matrix; granule G = rnd*256+wave*64+lane
  const short* gA[4]; const short* gB[4];
  short* ldsA[4]; short* ldsB[4];
  #pragma unroll
  for (int rnd = 0; rnd < 4; rnd++) {
    int G = rnd * 256 + wave * 64 + lane;
    int line = G >> 3, pos = G & 7, x = pos ^ (line & 7);
    gA[rnd] = A + (size_t)(row0 + line) * K + x * 8;
    gB[rnd] = Wt + (size_t)(n0 + line) * K + x * 8;
    ldsA[rnd] = &As[(rnd * 256 + wave * 64) * 8];
    ldsB[rnd] = &Bs[(rnd * 256 + wave * 64) * 8];
  }

  // fragment read addresses (fixed): row r, k-granule q=ks*4+quad,
  // granule = r*8 + (q ^ (r&7))
  const short* aF[2][4]; const short* bF[2][4];
  #pragma unroll
  for (int ks = 0; ks < 2; ks++) {
    #pragma unroll
    for (int t4 = 0; t4 < 4; t4++) {
      int r = wm * 64 + t4 * 16 + lr;
      int pos = (ks * 4 + quad) ^ (r & 7);
      aF[ks][t4] = &As[(r * 8 + pos) * 8];
      int rb = wn * 64 + t4 * 16 + lr;
      int posb = (ks * 4 + quad) ^ (rb & 7);
      bF[ks][t4] = &Bs[(rb * 8 + posb) * 8];
    }
  }

  f32x4 acc[4][4];
  #pragma unroll
  for (int i = 0; i < 4; i++)
    #pragma unroll
    for (int j = 0; j < 4; j++)
      #pragma unroll
      for (int e = 0; e < 4; e++) acc[i][j][e] = 0.f;

  for (int k0 = 0; k0 < K; k0 += 64) {
    #pragma unroll
    for (int rnd = 0; rnd < 4; rnd++) gload16(gA[rnd], ldsA[rnd]);
    #pragma unroll
    for (int rnd = 0; rnd < 4; rnd++) gload16(gB[rnd], ldsB[rnd]);
    #pragma unroll
    for (int rnd = 0; rnd < 4; rnd++) { gA[rnd] += 64; gB[rnd] += 64; }
    __syncthreads();
    #pragma unroll
    for (int ks = 0; ks < 2; ks++) {
      bf16x8 av[4], bv[4];
      #pragma unroll
      for (int t4 = 0; t4 < 4; t4++) {
        av[t4] = *(const bf16x8*)aF[ks][t4];
        bv[t4] = *(const bf16x8*)bF[ks][t4];
      }
      #pragma unroll
      for (int ct = 0; ct < 4; ct++)
        #pragma unroll
        for (int rt = 0; rt < 4; rt++)
          acc[rt][ct] = __builtin_amdgcn_mfma_f32_16x16x32_bf16(av[rt], bv[ct], acc[rt][ct], 0, 0, 0);
    }
    __syncthreads();
  }

  // epilogue: tile col = lane&15, row = quad*4+i
  #pragma unroll
  for (int ct = 0; ct < 4; ct++) {
    const int n = n0 + wn * 64 + ct * 16 + lr;
    const float bs = bias[n];
    const float gm = (EMODE == 2) ? gamma[n] : 0.f;
    #pragma unroll
    for (int rt = 0; rt < 4; rt++) {
      #pragma unroll
      for (int i = 0; i < 4; i++) {
        const int m = row0 + wm * 64 + rt * 16 + quad * 4 + i;
        float v = acc[rt][ct][i] + bs;
        if (EMODE == 0) {
          ((short*)Cout)[(size_t)m * N + n] = f2bf(v);
        } else if (EMODE == 1) {
          ((float*)Cout)[(size_t)m * N + n] = v;
        } else {
          ((float*)Cout)[(size_t)m * N + n] = qres[(size_t)m * N + n] + gm * v;
        }
      }
    }
  }
}

// ---------- sampler: softmax + bilinear gather + weighted sum ----------
// XCD-affinity block remap: each XCD owns 512 consecutive blocks = 2048
// consecutive queries = 2 batches; processed ~one batch (4.1 MB value) at a
// time => gathers mostly L2-hit instead of L3.
__global__ __launch_bounds__(384) void sampler_kernel(
    const float* __restrict__ offaw,  // [16384][512] (cols 448..511 unused)
    const float* __restrict__ refp,   // [B][LQ][3][2]
    const short* __restrict__ value,  // bf16 [B*5376][384]
    short* __restrict__ o) {          // bf16 [16384][384]
  const int tid = threadIdx.x;
  const int qi = tid / 96, t = tid % 96;
  const int head = t >> 3, ln4 = t & 7;
  const int blk = (blockIdx.x & 7) * 512 + (blockIdx.x >> 3);  // XCD-chunked
  const int bq = blk * 4 + qi;
  __shared__ __align__(16) float s[4][440];
  __shared__ float sref[4][6];
  const float* row = offaw + (size_t)bq * 512;
  #pragma unroll
  for (int i = t; i < 108; i += 96)
    *(float4*)&s[qi][i * 4] = *(const float4*)&row[i * 4];
  if (t < 6) sref[qi][t] = refp[(size_t)bq * 6 + t];
  __syncthreads();

  const float* awp = &s[qi][288 + head * 12];
  float mx = awp[0];
  #pragma unroll
  for (int j = 1; j < 12; j++) mx = fmaxf(mx, awp[j]);
  float wgt[12];
  float ssum = 0.f;
  #pragma unroll
  for (int j = 0; j < 12; j++) { float e = __expf(awp[j] - mx); wgt[j] = e; ssum += e; }
  const float inv = 1.f / ssum;

  const int b = bq >> 10;
  const unsigned short* vb =
      (const unsigned short*)value + (size_t)b * 5376 * 384 + head * 32 + ln4 * 4;
  float4 acc = make_float4(0.f, 0.f, 0.f, 0.f);
  const int HW[3] = {64, 32, 16};
  const int starts[3] = {0, 4096, 5120};
  #pragma unroll
  for (int l = 0; l < 3; l++) {
    const int Wi = HW[l];
    const float Wf = (float)Wi;
    const float rx = sref[qi][l * 2], ry = sref[qi][l * 2 + 1];
    const unsigned short* base = vb + (size_t)starts[l] * 384;
    #pragma unroll
    for (int p = 0; p < 4; p++) {
      const int oi = ((head * 3 + l) * 4 + p) * 2;
      float x = fmaf(rx, Wf, s[qi][oi] - 0.5f);
      float y = fmaf(ry, Wf, s[qi][oi + 1] - 0.5f);
      float xf = floorf(x), yf = floorf(y);
      float dx = x - xf, dy = y - yf;
      int x0 = (int)xf, y0 = (int)yf;
      int x1 = x0 + 1, y1 = y0 + 1;
      int x0c = min(max(x0, 0), Wi - 1), x1c = min(max(x1, 0), Wi - 1);
      int y0c = min(max(y0, 0), Wi - 1), y1c = min(max(y1, 0), Wi - 1);
      float wx0 = (x0 >= 0 && x0 < Wi) ? (1.f - dx) : 0.f;
      float wx1 = (x1 < Wi && x1 >= 0) ? dx : 0.f;
      float wy0 = (y0 >= 0 && y0 < Wi) ? (1.f - dy) : 0.f;
      float wy1 = (y1 < Wi && y1 >= 0) ? dy : 0.f;
      const ushort4 u00 = *(const ushort4*)(base + (size_t)(y0c * Wi + x0c) * 384);
      const ushort4 u01 = *(const ushort4*)(base + (size_t)(y0c * Wi + x1c) * 384);
      const ushort4 u10 = *(const ushort4*)(base + (size_t)(y1c * Wi + x0c) * 384);
      const ushort4 u11 = *(const ushort4*)(base + (size_t)(y1c * Wi + x1c) * 384);
      const float w00 = wx0 * wy0, w01 = wx1 * wy0, w10 = wx0 * wy1, w11 = wx1 * wy1;
      const float g = wgt[l * 4 + p];
      acc.x += g * (w00 * bf2f(u00.x) + w01 * bf2f(u01.x) + w10 * bf2f(u10.x) + w11 * bf2f(u11.x));
      acc.y += g * (w00 * bf2f(u00.y) + w01 * bf2f(u01.y) + w10 * bf2f(u10.y) + w11 * bf2f(u11.y));
      acc.z += g * (w00 * bf2f(u00.z) + w01 * bf2f(u01.z) + w10 * bf2f(u10.z) + w11 * bf2f(u11.z));
      acc.w += g * (w00 * bf2f(u00.w) + w01 * bf2f(u01.w) + w10 * bf2f(u10.w) + w11 * bf2f(u11.w));
    }
  }
  ushort4 outv;
  outv.x = (unsigned short)f2bf(acc.x * inv);
  outv.y = (unsigned short)f2bf(acc.y * inv);
  outv.z = (unsigned short)f2bf(acc.z * inv);
  outv.w = (unsigned short)f2bf(acc.w * inv);
  *(ushort4*)((unsigned short*)o + (size_t)bq * 384 + head * 32 + ln4 * 4) = outv;
}

// ---------- launch ----------
extern "C" void kernel_launch(void* const* d_in, const int* in_sizes, int n_in,
                              void* d_out, int out_size, void* d_ws, size_t ws_size,
                              hipStream_t stream) {
  (void)in_sizes; (void)n_in; (void)out_size; (void)ws_size;
  const float* q     = (const float*)d_in[0];
  const float* refp  = (const float*)d_in[1];
  const float* kv    = (const float*)d_in[2];
  const float* ln1w  = (const float*)d_in[5];
  const float* ln1b  = (const float*)d_in[6];
  const float* ln2w  = (const float*)d_in[7];
  const float* ln2b  = (const float*)d_in[8];
  const float* gamma = (const float*)d_in[9];
  const float* w_off = (const float*)d_in[10];
  const float* b_off = (const float*)d_in[11];
  const float* w_aw  = (const float*)d_in[12];
  const float* b_aw  = (const float*)d_in[13];
  const float* w_val = (const float*)d_in[14];
  const float* b_val = (const float*)d_in[15];
  const float* w_out = (const float*)d_in[16];
  const float* b_out = (const float*)d_in[17];
  float* out = (float*)d_out;

  char* wsp = (char*)d_ws;
  size_t cur = 0;
  auto alloc = [&](size_t bytes) -> void* {
    cur = (cur + 255) & ~(size_t)255;
    void* p = wsp + cur;
    cur += bytes;
    return p;
  };
  short*  wT_val   = (short*)alloc((size_t)384 * 768 * 2);
  short*  wT_offaw = (short*)alloc((size_t)512 * 768 * 2);
  short*  wT_out   = (short*)alloc((size_t)768 * 384 * 2);
  float*  bias_cat = (float*)alloc((size_t)512 * 4);
  short*  kvn      = (short*)alloc((size_t)86016 * 768 * 2);
  short*  qn       = (short*)alloc((size_t)16384 * 768 * 2);
  short*  value    = (short*)alloc((size_t)86016 * 384 * 2);
  float*  offaw    = (float*)alloc((size_t)16384 * 512 * 4);
  short*  obuf     = (short*)alloc((size_t)16384 * 384 * 2);

  pack_weights_kernel<<<3842, 256, 0, stream>>>(w_val, w_off, w_aw, w_out, b_off,
                                                b_aw, wT_val, wT_offaw, wT_out,
                                                bias_cat);
  ln_norm4_kernel<<<21504, 256, 0, stream>>>(kv, ln2w, ln2b, kvn);
  ln_norm4_kernel<<<4096, 256, 0, stream>>>(q, ln1w, ln1b, qn);
  // value = kvn @ w_val + b_val   (M=86016, N=384, K=768) -> bf16
  gemm128_kernel<0><<<dim3(3, 672), 256, 0, stream>>>(
      kvn, wT_val, b_val, nullptr, nullptr, value, 384, 768);
  // offaw = qn @ [w_off|w_aw|pad] + bias  (M=16384, N=512(pad), K=768) -> f32
  gemm128_kernel<1><<<dim3(4, 128), 256, 0, stream>>>(
      qn, wT_offaw, bias_cat, nullptr, nullptr, offaw, 512, 768);
  // sampling + attention-weighted sum -> obuf bf16 (16384 x 384)
  sampler_kernel<<<4096, 384, 0, stream>>>(offaw, refp, value, obuf);
  // out = q + gamma * (obuf @ w_out + b_out)  (M=16384, N=768, K=384)
  gemm128_kernel<2><<<dim3(6, 128), 256, 0, stream>>>(
      obuf, wT_out, b_out, q, gamma, out, 768, 384);
}